// Round 9
// baseline (347.745 us; speedup 1.0000x reference)
//
#include <hip/hip_runtime.h>
#include <math.h>

#define QPIX 16384

typedef __bf16 bf16x8 __attribute__((ext_vector_type(8)));
typedef float f32x4 __attribute__((ext_vector_type(4)));
typedef unsigned short ushort8v __attribute__((ext_vector_type(8)));

__device__ __forceinline__ unsigned short f2b(float f) {
  unsigned int x = __float_as_uint(f);
  unsigned int r = (x + 0x7fff + ((x >> 16) & 1)) >> 16;
  return (unsigned short)r;
}
__device__ __forceinline__ float b2f(unsigned short u) {
  return __uint_as_float(((unsigned int)u) << 16);
}

__device__ __forceinline__ void gld_lds16(const void* g, void* l) {
  __builtin_amdgcn_global_load_lds((__attribute__((address_space(1))) void*)(g),
                                   (__attribute__((address_space(3))) void*)(l), 16, 0, 0);
}

// swizzled element offset within a [rows][64]-bf16 LDS tile (16B-slot XOR row&7)
__device__ __forceinline__ int swz(int row, int ebase) {
  return row * 64 + ((((ebase) >> 3) ^ (row & 7)) << 3);
}

// ---------------- all input conversions in ONE dispatch (+ zero/counter init) ----------------
__global__ __launch_bounds__(256) void k_cvt_all(
    const float* __restrict__ feats, const float* __restrict__ bevq,
    const float* __restrict__ w1, const float* __restrict__ w2,
    const float* __restrict__ w3, const float* __restrict__ wo,
    const float* __restrict__ wi, unsigned short* __restrict__ featTb,
    unsigned short* __restrict__ qhi, unsigned short* __restrict__ qlo,
    unsigned short* __restrict__ w1b, unsigned short* __restrict__ w2b,
    unsigned short* __restrict__ w3b, unsigned short* __restrict__ wob,
    unsigned short* __restrict__ wibh, unsigned short* __restrict__ wibl,
    float* __restrict__ zerof) {
  __shared__ float tile[128][33];
  const int b = blockIdx.x, t = threadIdx.x;
  if (b == 0 && t < 176) zerof[t] = 0.f;  // zero staging buf + stats counters
  if (b < 528) {
    const int img = b / 88;
    const int pb = (b - img * 88) * 32;
    const int p = t & 31, cg = t >> 5;
#pragma unroll
    for (int ci = 0; ci < 16; ++ci) {
      const int c = cg * 16 + ci;
      tile[c][p] = feats[((size_t)img * 128 + c) * 2816 + pb + p];
    }
    __syncthreads();
    const int c2 = t & 127, pw = t >> 7;
#pragma unroll
    for (int pp = pw; pp < 32; pp += 2)
      featTb[(size_t)img * 2816 * 128 + (size_t)(pb + pp) * 128 + c2] = f2b(tile[c2][pp]);
  } else if (b < 1040) {
    const int pb = (b - 528) * 32;
    const int p = t & 31, cg = t >> 5;
#pragma unroll
    for (int ci = 0; ci < 16; ++ci) {
      const int c = cg * 16 + ci;
      tile[c][p] = bevq[(size_t)c * QPIX + pb + p];
    }
    __syncthreads();
    const int c2 = t & 127, pw = t >> 7;
#pragma unroll
    for (int pp = pw; pp < 32; pp += 2) {
      float v = tile[c2][pp];
      unsigned short h = f2b(v);
      qhi[(size_t)(pb + pp) * 128 + c2] = h;
      qlo[(size_t)(pb + pp) * 128 + c2] = f2b(v - b2f(h));
    }
  } else {
    const int bb = b - 1040;
    if (bb < 1024) {
      int i = bb * 256 + t;
      w1b[i] = f2b(w1[i]);
    } else if (bb < 2048) {
      int i = (bb - 1024) * 256 + t;
      w2b[i] = f2b(w2[i]);
    } else if (bb < 2304) {
      int i = (bb - 2048) * 256 + t;
      w3b[i] = f2b(w3[i]);
    } else if (bb < 2880) {
      int i = (bb - 2304) * 256 + t;
      int n = i & 127, kk = i >> 7;
      int tap = kk >> 7, ci = kk & 127;
      wob[(size_t)n * 1152 + kk] = f2b(wo[(size_t)tap * 16384 + ci * 128 + n]);
    } else {
      int i = (bb - 2880) * 256 + t;
      int n = i & 127, kk = i >> 7;
      int tap = kk >> 7, ci = kk & 127;
      float v = wi[(size_t)tap * 16384 + ci * 128 + n];
      unsigned short h = f2b(v);
      wibh[(size_t)n * 1152 + kk] = h;
      wibl[(size_t)n * 1152 + kk] = f2b(v - b2f(h));
    }
  }
}

// ---------------- bf16 MFMA GEMM, T2-swizzled LDS, fused stats + last-block finale ----------------
// Out[M,N] = act( A @ Wt^T + bias (+resid) ), Wt is [N][K] bf16 row-major.
// MODE: 0 plain A [M][K]; 1 conv3x3 im2col from NHWC bf16; 2 conv im2col split precision.
// ACT: 0 none, 1 exact gelu.
// RES: 0 none, 1 fp32 NHWC resid, 2 fp32 NCHW resid, 3 NHWC inline-norm resid ((resid-m)*r).
// OBF: 1 bf16 out, 0 fp32 out.
// STATS: 1 -> per-block per-channel sum/ssq to partial[yblk*128 + n0+c]; last of the 512
//        blocks (atomic counter) reduces all partials -> mrout (mean + rsqrt).
template <int BM, int BN, int MODE, int ACT, int RES, int OBF, int STATS>
__global__ __launch_bounds__(256) void mfma_gemm(
    const unsigned short* __restrict__ A, const unsigned short* __restrict__ A2,
    const unsigned short* __restrict__ Wt, const unsigned short* __restrict__ Wt2,
    const float* __restrict__ bias, const float* __restrict__ resid,
    const float* __restrict__ mrres, void* __restrict__ Out,
    float* __restrict__ partial, unsigned* __restrict__ cnt,
    float* __restrict__ mrout, int N, int K,
    const unsigned short* __restrict__ zbuf) {
  constexpr int MI = BM / 32;
  constexpr int NJ = BN / 32;
  __shared__ unsigned short As[BM * 64];
  __shared__ unsigned short Bs[BN * 64];
  __shared__ unsigned short As2[(MODE == 2) ? BM * 64 : 1];
  __shared__ unsigned short Bs2[(MODE == 2) ? BN * 64 : 1];
  __shared__ float sred[STATS ? (BM / 8) : 1][STATS ? BN : 1];
  __shared__ float ssred[STATS ? (BM / 8) : 1][STATS ? BN : 1];
  __shared__ unsigned lastv;

  const int t = threadIdx.x;
  const int lane = t & 63, w = t >> 6;
  const int wr = w >> 1, wc = w & 1;
  const int n0 = blockIdx.x * BN;
  const int m0 = blockIdx.y * BM;

  const int lrow = lane >> 3;
  const int akk = (((lane & 7) ^ (lrow & 7))) * 8;  // T2 pre-swizzled source k-slot
  const int arow_l = wr * (BM / 2) + (lane & 15);
  const int brow_l = wc * (BN / 2) + (lane & 15);
  const int klane = (lane >> 4) * 8;

  f32x4 acc[MI][NJ];
#pragma unroll
  for (int i = 0; i < MI; ++i)
#pragma unroll
    for (int j = 0; j < NJ; ++j) acc[i][j] = (f32x4){0.f, 0.f, 0.f, 0.f};

  for (int k0 = 0; k0 < K; k0 += 64) {
#pragma unroll
    for (int q = 0; q < BM / 32; ++q) {
      const int r0 = w * (BM / 4) + q * 8;
      const int arow = r0 + lrow;
      const unsigned short* asrc;
      const unsigned short* asrc2 = zbuf;
      if (MODE == 0) {
        asrc = A + (size_t)(m0 + arow) * K + k0 + akk;
      } else {
        const int tap = k0 >> 7;
        const int dy = tap / 3 - 1, dx = tap % 3 - 1;
        const int pix = m0 + arow;
        const int hs = (pix >> 7) + dy;
        const int xs = (pix & 127) + dx;
        const bool ok = (hs >= 0) && (hs < 128) && (xs >= 0) && (xs < 128);
        const size_t srcoff = (size_t)((hs << 7) | (xs & 127)) * 128 + (k0 & 127) + akk;
        asrc = ok ? A + srcoff : zbuf;
        if (MODE == 2) asrc2 = ok ? A2 + srcoff : zbuf;
      }
      gld_lds16(asrc, &As[r0 * 64]);
      if (MODE == 2) gld_lds16(asrc2, &As2[r0 * 64]);
    }
#pragma unroll
    for (int q = 0; q < BN / 32; ++q) {
      const int r0 = w * (BN / 4) + q * 8;
      const int brow = r0 + lrow;
      gld_lds16(Wt + (size_t)(n0 + brow) * K + k0 + akk, &Bs[r0 * 64]);
      if (MODE == 2)
        gld_lds16(Wt2 + (size_t)(n0 + brow) * K + k0 + akk, &Bs2[r0 * 64]);
    }
    __syncthreads();
#pragma unroll
    for (int ks = 0; ks < 64; ks += 32) {
      bf16x8 af[MI], bfv[NJ];
#pragma unroll
      for (int i = 0; i < MI; ++i)
        af[i] = *(const bf16x8*)&As[swz(arow_l + i * 16, ks + klane)];
#pragma unroll
      for (int j = 0; j < NJ; ++j)
        bfv[j] = *(const bf16x8*)&Bs[swz(brow_l + j * 16, ks + klane)];
#pragma unroll
      for (int i = 0; i < MI; ++i)
#pragma unroll
        for (int j = 0; j < NJ; ++j)
          acc[i][j] = __builtin_amdgcn_mfma_f32_16x16x32_bf16(af[i], bfv[j], acc[i][j], 0, 0, 0);
      if (MODE == 2) {
        bf16x8 af2[MI], bf2[NJ];
#pragma unroll
        for (int i = 0; i < MI; ++i)
          af2[i] = *(const bf16x8*)&As2[swz(arow_l + i * 16, ks + klane)];
#pragma unroll
        for (int j = 0; j < NJ; ++j)
          bf2[j] = *(const bf16x8*)&Bs2[swz(brow_l + j * 16, ks + klane)];
#pragma unroll
        for (int i = 0; i < MI; ++i)
#pragma unroll
          for (int j = 0; j < NJ; ++j) {
            acc[i][j] = __builtin_amdgcn_mfma_f32_16x16x32_bf16(af[i], bf2[j], acc[i][j], 0, 0, 0);
            acc[i][j] = __builtin_amdgcn_mfma_f32_16x16x32_bf16(af2[i], bfv[j], acc[i][j], 0, 0, 0);
          }
      }
    }
    __syncthreads();
  }
  // ---- epilogue ----
  float sj[NJ], ssj[NJ];
#pragma unroll
  for (int j = 0; j < NJ; ++j) { sj[j] = 0.f; ssj[j] = 0.f; }
#pragma unroll
  for (int i = 0; i < MI; ++i) {
    const int mrow = m0 + wr * (BM / 2) + i * 16 + (lane >> 4) * 4;
#pragma unroll
    for (int j = 0; j < NJ; ++j) {
      const int col = n0 + wc * (BN / 2) + j * 16 + (lane & 15);
      const float bz = bias[col];
#pragma unroll
      for (int r = 0; r < 4; ++r) {
        const int m = mrow + r;
        float v = acc[i][j][r] + bz;
        if (RES == 1) v += resid[(size_t)m * 128 + col];
        if (RES == 2) v += resid[(size_t)col * QPIX + m];
        if (RES == 3)
          v += (resid[(size_t)m * 128 + col] - mrres[col]) * mrres[128 + col];
        if (ACT == 1) v = 0.5f * v * (1.f + erff(v * 0.70710678118654752f));
        if (OBF)
          ((unsigned short*)Out)[(size_t)m * N + col] = f2b(v);
        else
          ((float*)Out)[(size_t)m * N + col] = v;
        if (STATS) {
          sj[j] += v;
          ssj[j] += v * v;
        }
      }
    }
  }
  if (STATS) {
    const int cidx = wr * 4 + (lane >> 4);
#pragma unroll
    for (int j = 0; j < NJ; ++j) {
      const int cl = wc * (BN / 2) + j * 16 + (lane & 15);
      sred[cidx][cl] = sj[j];
      ssred[cidx][cl] = ssj[j];
    }
    __syncthreads();
    if (t < BN) {
      float s = 0.f, ss = 0.f;
#pragma unroll
      for (int kk = 0; kk < BM / 8; ++kk) {
        s += sred[kk][t];
        ss += ssred[kk][t];
      }
      partial[(size_t)blockIdx.y * 128 + n0 + t] = s;
      partial[32768 + (size_t)blockIdx.y * 128 + n0 + t] = ss;
    }
    __threadfence();
    __syncthreads();
    if (t == 0) lastv = atomicAdd(cnt, 1u);
    __syncthreads();
    if (lastv == gridDim.x * gridDim.y - 1) {
      __threadfence();
      if (t < 128) {
        float s = 0.f, ss = 0.f;
#pragma unroll 4
        for (int y = 0; y < 256; ++y) {
          s += partial[(size_t)y * 128 + t];
          ss += partial[32768 + (size_t)y * 128 + t];
        }
        float m = s * (1.f / 16384.f);
        float var = ss * (1.f / 16384.f) - m * m;
        mrout[t] = m;
        mrout[128 + t] = rsqrtf(var + 1e-5f);
      }
    }
  }
}

// ---------------- inorm apply + offset head + projection + gather, one kernel ----------------
// 1024 blocks x 16 queries. Gather: lane owns an 8-channel slice, loops cams x corners.
__global__ __launch_bounds__(256) void k_offgather(
    const float* __restrict__ tB, const float* __restrict__ mr,
    const float* __restrict__ offw, const float* __restrict__ offb,
    const float* __restrict__ bpos, const float* __restrict__ l2i,
    const unsigned short* __restrict__ featT,
    unsigned short* __restrict__ sampled) {
  __shared__ float wT[128 * 12];
  __shared__ float bl[12];
  __shared__ float Ll[96];
  __shared__ float ml[128], rl[128];
  __shared__ float ldsq[16 * 130];
  __shared__ float offl[16 * 12];
  __shared__ float cw[16 * 24 * 4];
  __shared__ int cidx[16 * 24 * 4];
  const int t = threadIdx.x;
  const int qb = blockIdx.x * 16;
  // phase 0: constants + raw q rows into registers
  for (int i = t; i < 1536; i += 256) wT[(i & 127) * 12 + (i >> 7)] = offw[i];
  if (t < 12) bl[t] = offb[t];
  if (t < 96) Ll[t] = l2i[t];
  if (t < 128) {
    ml[t] = mr[t];
    rl[t] = mr[128 + t];
  }
  float4 ra = *(const float4*)&tB[(size_t)qb * 128 + t * 8];
  float4 rb = *(const float4*)&tB[(size_t)qb * 128 + t * 8 + 4];
  __syncthreads();
  // phase A: normalize into ldsq
  {
    const int e = t * 8;
    const int q = e >> 7, c0 = e & 127;
    float* d = &ldsq[q * 130 + c0];
    const float va[8] = {ra.x, ra.y, ra.z, ra.w, rb.x, rb.y, rb.z, rb.w};
#pragma unroll
    for (int u = 0; u < 8; ++u) d[u] = (va[u] - ml[c0 + u]) * rl[c0 + u];
  }
  __syncthreads();
  // phase B: 192 offset dots + sigmoid
  if (t < 192) {
    const int q = t / 12, o = t - (t / 12) * 12;
    float acc = bl[o];
    for (int c = 0; c < 128; ++c) acc += ldsq[q * 130 + c] * wT[c * 12 + o];
    offl[q * 12 + o] = 1.f / (1.f + expf(-acc));
  }
  __syncthreads();
  // phase C: 384 projection items -> corner weights/indices in LDS
  const float EPSf = 1e-5f;
#pragma unroll
  for (int ii = 0; ii < 2; ++ii) {
    const int item = ii * 256 + t;
    if (item < 384) {
      const int ql = item / 24;
      const int j = item - ql * 24;
      const int p = j / 6, n = j - p * 6;
      const int q = qb + ql;
      float o0 = offl[ql * 12 + p * 3 + 0];
      float o1 = offl[ql * 12 + p * 3 + 1];
      float o2 = offl[ql * 12 + p * 3 + 2];
      float ox = o0 * ((0.25f + EPSf) * 2.f) - (0.25f + EPSf);
      float oy = o1 * ((0.25f + EPSf) * 2.f) - (0.25f + EPSf);
      float oz = o2 * ((4.f + EPSf) * 2.f) - (4.f + EPSf);
      float px = bpos[q * 3 + 0] * 102.4f - 51.2f + ox;
      float py = bpos[q * 3 + 1] * 102.4f - 51.2f + oy;
      float pz = bpos[q * 3 + 2] * 8.f - 5.f + oz;
      const float* L = Ll + n * 16;
      float c0 = L[0] * px + L[1] * py + L[2] * pz + L[3];
      float c1 = L[4] * px + L[5] * py + L[6] * pz + L[7];
      float c2 = L[8] * px + L[9] * py + L[10] * pz + L[11];
      float d = fmaxf(c2, EPSf);
      float u = (c0 / d) / 704.f;
      float v = (c1 / d) / 256.f;
      float valid = (c2 > EPSf && u > 0.f && u < 1.f && v > 0.f && v < 1.f) ? 1.f : 0.f;
      float x = u * 88.f - 0.5f;
      float y = v * 32.f - 0.5f;
      float x0 = floorf(x), y0 = floorf(y);
      float wx1 = x - x0, wy1 = y - y0;
      float wx0 = 1.f - wx1, wy0 = 1.f - wy1;
#pragma unroll
      for (int k = 0; k < 4; ++k) {
        float xf = x0 + (float)(k & 1);
        float yf = y0 + (float)(k >> 1);
        bool inb = (xf >= 0.f) && (xf <= 87.f) && (yf >= 0.f) && (yf <= 31.f);
        float xc = fminf(fmaxf(xf, 0.f), 87.f);
        float yc = fminf(fmaxf(yf, 0.f), 31.f);
        cidx[ql * 96 + j * 4 + k] = ((n * 32 + (int)yc) * 88 + (int)xc) * 128;
        float wgt = ((k & 1) ? wx1 : wx0) * ((k >> 1) ? wy1 : wy0);
        cw[ql * 96 + j * 4 + k] = inb ? wgt * valid : 0.f;
      }
    }
  }
  __syncthreads();
  // phase D: gather — lane owns 8 channels; serial over 6 cams x 4 corners
  const int e8 = (t & 15) * 8;
#pragma unroll
  for (int rep = 0; rep < 4; ++rep) {
    const int unit = rep * 16 + (t >> 4);
    const int q = unit >> 2, p = unit & 3;
    float s[8] = {0.f, 0.f, 0.f, 0.f, 0.f, 0.f, 0.f, 0.f};
    const float* cwp = &cw[q * 96 + p * 24];
    const int* cip = &cidx[q * 96 + p * 24];
#pragma unroll
    for (int cc = 0; cc < 24; ++cc) {
      const float wv = cwp[cc];
      if (wv != 0.f) {
        ushort8v v = *(const ushort8v*)&featT[(size_t)cip[cc] + e8];
#pragma unroll
        for (int u = 0; u < 8; ++u) s[u] += wv * b2f(v[u]);
      }
    }
    ushort8v o8;
#pragma unroll
    for (int u = 0; u < 8; ++u) o8[u] = f2b(s[u]);
    *(ushort8v*)&sampled[(size_t)(qb + q) * 512 + p * 128 + e8] = o8;
  }
}

// ---------------- apply: norm(a) -> bf16, vectorized ----------------
__global__ __launch_bounds__(256) void k_apply2(const float* __restrict__ a,
                                                const float* __restrict__ mr,
                                                unsigned short* __restrict__ outb) {
  const size_t i = ((size_t)blockIdx.x * 256 + threadIdx.x) * 4;
  const int c = (int)(i & 127);
  float4 v = *(const float4*)&a[i];
  ushort4 o;
  o.x = f2b((v.x - mr[c]) * mr[128 + c]);
  o.y = f2b((v.y - mr[c + 1]) * mr[128 + c + 1]);
  o.z = f2b((v.z - mr[c + 2]) * mr[128 + c + 2]);
  o.w = f2b((v.w - mr[c + 3]) * mr[128 + c + 3]);
  *(ushort4*)&outb[i] = o;
}

// ---------------- final apply: norm(a) + NHWC->NCHW via LDS tiles ----------------
__global__ __launch_bounds__(256) void k_apply_t(const float* __restrict__ a,
                                                 const float* __restrict__ mr,
                                                 float* __restrict__ out) {
  __shared__ float tile[128][33];
  __shared__ float ml[128], rl[128];
  const int t = threadIdx.x;
  const int pb = blockIdx.x * 32;
  if (t < 128) {
    ml[t] = mr[t];
    rl[t] = mr[128 + t];
  }
  __syncthreads();
#pragma unroll
  for (int j = 0; j < 16; ++j) {
    const int e = j * 256 + t;
    const int pl = e >> 7, c = e & 127;
    const size_t gi = (size_t)(pb + pl) * 128 + c;
    tile[c][pl] = (a[gi] - ml[c]) * rl[c];
  }
  __syncthreads();
  const int p = t & 31, cb = t >> 5;
#pragma unroll
  for (int j = 0; j < 16; ++j) {
    const int c = cb + j * 8;
    out[(size_t)c * QPIX + pb + p] = tile[c][p];
  }
}

extern "C" void kernel_launch(void* const* d_in, const int* in_sizes, int n_in,
                              void* d_out, int out_size, void* d_ws, size_t ws_size,
                              hipStream_t stream) {
  const float* feats = (const float*)d_in[0];
  const float* l2i   = (const float*)d_in[1];
  const float* bevq  = (const float*)d_in[2];
  const float* bpos  = (const float*)d_in[3];
  const float* w_in  = (const float*)d_in[4];
  const float* b_in  = (const float*)d_in[5];
  const float* offw  = (const float*)d_in[6];
  const float* offb  = (const float*)d_in[7];
  const float* w1    = (const float*)d_in[8];
  const float* b1    = (const float*)d_in[9];
  const float* w2    = (const float*)d_in[10];
  const float* b2    = (const float*)d_in[11];
  const float* w3    = (const float*)d_in[12];
  const float* b3    = (const float*)d_in[13];
  const float* w_out = (const float*)d_in[14];
  const float* b_out = (const float*)d_in[15];
  float* out = (float*)d_out;

  const size_t QC = (size_t)QPIX * 128;
  float* ws = (float*)d_ws;
  float* tA = ws;                         // 2,097,152  conv1 out -> conv2 out
  float* tBb = tA + QC;                   // 2,097,152  mm3 out
  float* partial = tBb + QC;              // 65,536 ([256 yblk][128 c] sum + ssq)
  float* mr1 = partial + 65536;           // 256
  float* mr2 = mr1 + 256;                 // 256
  float* mr3 = mr2 + 256;                 // 256
  float* zerof = mr3 + 256;               // 160 zero staging + 16 counter slots
  unsigned* cnts = (unsigned*)(zerof + 160);
  unsigned short* us = (unsigned short*)(zerof + 176);
  unsigned short* S1b = us;               // 8,388,608 (sampled -> x2)
  unsigned short* S2b = S1b + 8388608;    // 8,388,608 (x1)
  unsigned short* featTb = S2b + 8388608; // 2,162,688
  unsigned short* qhi = featTb + 2162688; // 2,097,152 (conv1 hi; later q2 bf16)
  unsigned short* qlo = qhi + 2097152;    // 2,097,152
  unsigned short* w1b = qlo + 2097152;    // 262,144
  unsigned short* w2b = w1b + 262144;     // 262,144
  unsigned short* w3b = w2b + 262144;     // 65,536
  unsigned short* wob = w3b + 65536;      // 147,456
  unsigned short* wibh = wob + 147456;    // 147,456
  unsigned short* wibl = wibh + 147456;   // 147,456
  const unsigned short* zb = (const unsigned short*)zerof;

  dim3 blk(256);

  // all conversions + zero/counter init, one dispatch
  k_cvt_all<<<4496, blk, 0, stream>>>(feats, bevq, w1, w2, w3, w_out, w_in,
                                      featTb, qhi, qlo, w1b, w2b, w3b, wob, wibh,
                                      wibl, zerof);

  // t1 = q + conv3x3(q)  (split-precision bf16 MFMA, fused stats + finale -> mr1)
  mfma_gemm<64, 64, 2, 0, 2, 0, 1><<<dim3(2, 256), blk, 0, stream>>>(
      qhi, qlo, wibh, wibl, b_in, bevq, nullptr, tA, partial, &cnts[0], mr1,
      128, 1152, zb);

  // inorm(t1) -> offset head -> projection -> gather, one kernel
  k_offgather<<<1024, blk, 0, stream>>>(tA, mr1, offw, offb, bpos, l2i, featTb, S1b);

  // mid MLP
  mfma_gemm<128, 128, 0, 1, 0, 1, 0><<<dim3(4, 128), blk, 0, stream>>>(
      S1b, nullptr, w1b, nullptr, b1, nullptr, nullptr, S2b, nullptr, nullptr,
      nullptr, 512, 512, zb);
  mfma_gemm<128, 128, 0, 1, 0, 1, 0><<<dim3(4, 128), blk, 0, stream>>>(
      S2b, nullptr, w2b, nullptr, b2, nullptr, nullptr, S1b, nullptr, nullptr,
      nullptr, 512, 512, zb);
  // mm3: x3 + inline-norm(t1) residual, fused stats + finale -> mr2
  mfma_gemm<64, 64, 0, 0, 3, 0, 1><<<dim3(2, 256), blk, 0, stream>>>(
      S1b, nullptr, w3b, nullptr, b3, tA, mr1, tBb, partial, &cnts[1], mr2,
      128, 512, zb);
  k_apply2<<<2048, blk, 0, stream>>>(tBb, mr2, qhi);  // q2 bf16 for conv2 A

  // t2 = q2 + conv3x3(q2)  (bf16 MFMA im2col, inline-norm residual, finale -> mr3)
  mfma_gemm<64, 64, 1, 0, 3, 0, 1><<<dim3(2, 256), blk, 0, stream>>>(
      qhi, nullptr, wob, nullptr, b_out, tBb, mr2, tA, partial, &cnts[2], mr3,
      128, 1152, zb);
  k_apply_t<<<512, blk, 0, stream>>>(tA, mr3, out);
}

// Round 10
// 139.784 us; speedup vs baseline: 2.4877x; 2.4877x over previous
//
#include <hip/hip_runtime.h>
#include <math.h>

#define QPIX 16384

typedef __bf16 bf16x8 __attribute__((ext_vector_type(8)));
typedef float f32x4 __attribute__((ext_vector_type(4)));
typedef unsigned short ushort8v __attribute__((ext_vector_type(8)));

__device__ __forceinline__ unsigned short f2b(float f) {
  unsigned int x = __float_as_uint(f);
  unsigned int r = (x + 0x7fff + ((x >> 16) & 1)) >> 16;
  return (unsigned short)r;
}
__device__ __forceinline__ float b2f(unsigned short u) {
  return __uint_as_float(((unsigned int)u) << 16);
}

__device__ __forceinline__ void gld_lds16(const void* g, void* l) {
  __builtin_amdgcn_global_load_lds((__attribute__((address_space(1))) void*)(g),
                                   (__attribute__((address_space(3))) void*)(l), 16, 0, 0);
}

// swizzled element offset within a [rows][64]-bf16 LDS tile (16B-slot XOR row&7)
__device__ __forceinline__ int swz(int row, int ebase) {
  return row * 64 + ((((ebase) >> 3) ^ (row & 7)) << 3);
}

// ---------------- all input conversions in ONE dispatch (+ zero-buffer init) ----------------
__global__ __launch_bounds__(256) void k_cvt_all(
    const float* __restrict__ feats, const float* __restrict__ bevq,
    const float* __restrict__ w1, const float* __restrict__ w2,
    const float* __restrict__ w3, const float* __restrict__ wo,
    const float* __restrict__ wi, unsigned short* __restrict__ featTb,
    unsigned short* __restrict__ qhi, unsigned short* __restrict__ qlo,
    unsigned short* __restrict__ w1b, unsigned short* __restrict__ w2b,
    unsigned short* __restrict__ w3b, unsigned short* __restrict__ wob,
    unsigned short* __restrict__ wibh, unsigned short* __restrict__ wibl,
    float* __restrict__ zerof) {
  __shared__ float tile[128][33];
  const int b = blockIdx.x, t = threadIdx.x;
  if (b == 0 && t < 160) zerof[t] = 0.f;
  if (b < 528) {
    const int img = b / 88;
    const int pb = (b - img * 88) * 32;
    const int p = t & 31, cg = t >> 5;
#pragma unroll
    for (int ci = 0; ci < 16; ++ci) {
      const int c = cg * 16 + ci;
      tile[c][p] = feats[((size_t)img * 128 + c) * 2816 + pb + p];
    }
    __syncthreads();
    const int c2 = t & 127, pw = t >> 7;
#pragma unroll
    for (int pp = pw; pp < 32; pp += 2)
      featTb[(size_t)img * 2816 * 128 + (size_t)(pb + pp) * 128 + c2] = f2b(tile[c2][pp]);
  } else if (b < 1040) {
    const int pb = (b - 528) * 32;
    const int p = t & 31, cg = t >> 5;
#pragma unroll
    for (int ci = 0; ci < 16; ++ci) {
      const int c = cg * 16 + ci;
      tile[c][p] = bevq[(size_t)c * QPIX + pb + p];
    }
    __syncthreads();
    const int c2 = t & 127, pw = t >> 7;
#pragma unroll
    for (int pp = pw; pp < 32; pp += 2) {
      float v = tile[c2][pp];
      unsigned short h = f2b(v);
      qhi[(size_t)(pb + pp) * 128 + c2] = h;
      qlo[(size_t)(pb + pp) * 128 + c2] = f2b(v - b2f(h));
    }
  } else {
    const int bb = b - 1040;
    if (bb < 1024) {
      int i = bb * 256 + t;
      w1b[i] = f2b(w1[i]);
    } else if (bb < 2048) {
      int i = (bb - 1024) * 256 + t;
      w2b[i] = f2b(w2[i]);
    } else if (bb < 2304) {
      int i = (bb - 2048) * 256 + t;
      w3b[i] = f2b(w3[i]);
    } else if (bb < 2880) {
      int i = (bb - 2304) * 256 + t;
      int n = i & 127, kk = i >> 7;
      int tap = kk >> 7, ci = kk & 127;
      wob[(size_t)n * 1152 + kk] = f2b(wo[(size_t)tap * 16384 + ci * 128 + n]);
    } else {
      int i = (bb - 2880) * 256 + t;
      int n = i & 127, kk = i >> 7;
      int tap = kk >> 7, ci = kk & 127;
      float v = wi[(size_t)tap * 16384 + ci * 128 + n];
      unsigned short h = f2b(v);
      wibh[(size_t)n * 1152 + kk] = h;
      wibl[(size_t)n * 1152 + kk] = f2b(v - b2f(h));
    }
  }
}

// ---------------- bf16 MFMA GEMM, T2-swizzled LDS, optional fused stats partials ----------------
// Out[M,N] = act( A @ Wt^T + bias (+resid) ), Wt is [N][K] bf16 row-major.
// MODE: 0 plain A [M][K]; 1 conv3x3 im2col from NHWC bf16; 2 conv im2col split precision.
// ACT: 0 none, 1 exact gelu.
// RES: 0 none, 1 fp32 NHWC resid, 2 fp32 NCHW resid, 3 NHWC inline-norm resid ((resid-m)*r).
// OBF: 1 bf16 out, 0 fp32 out.
// STATS: 1 -> per-block per-channel sum/ssq to partial[(n0+c)*256 + blockIdx.y] (gridDim.y==256).
template <int BM, int BN, int MODE, int ACT, int RES, int OBF, int STATS>
__global__ __launch_bounds__(256) void mfma_gemm(
    const unsigned short* __restrict__ A, const unsigned short* __restrict__ A2,
    const unsigned short* __restrict__ Wt, const unsigned short* __restrict__ Wt2,
    const float* __restrict__ bias, const float* __restrict__ resid,
    const float* __restrict__ mrres, void* __restrict__ Out,
    float* __restrict__ partial, int N, int K,
    const unsigned short* __restrict__ zbuf) {
  constexpr int MI = BM / 32;
  constexpr int NJ = BN / 32;
  __shared__ unsigned short As[BM * 64];
  __shared__ unsigned short Bs[BN * 64];
  __shared__ unsigned short As2[(MODE == 2) ? BM * 64 : 1];
  __shared__ unsigned short Bs2[(MODE == 2) ? BN * 64 : 1];
  __shared__ float sred[STATS ? (BM / 8) : 1][STATS ? BN : 1];
  __shared__ float ssred[STATS ? (BM / 8) : 1][STATS ? BN : 1];

  const int t = threadIdx.x;
  const int lane = t & 63, w = t >> 6;
  const int wr = w >> 1, wc = w & 1;
  const int n0 = blockIdx.x * BN;
  const int m0 = blockIdx.y * BM;

  const int lrow = lane >> 3;
  const int akk = (((lane & 7) ^ (lrow & 7))) * 8;  // T2 pre-swizzled source k-slot
  const int arow_l = wr * (BM / 2) + (lane & 15);
  const int brow_l = wc * (BN / 2) + (lane & 15);
  const int klane = (lane >> 4) * 8;

  f32x4 acc[MI][NJ];
#pragma unroll
  for (int i = 0; i < MI; ++i)
#pragma unroll
    for (int j = 0; j < NJ; ++j) acc[i][j] = (f32x4){0.f, 0.f, 0.f, 0.f};

  for (int k0 = 0; k0 < K; k0 += 64) {
#pragma unroll
    for (int q = 0; q < BM / 32; ++q) {
      const int r0 = w * (BM / 4) + q * 8;
      const int arow = r0 + lrow;
      const unsigned short* asrc;
      const unsigned short* asrc2 = zbuf;
      if (MODE == 0) {
        asrc = A + (size_t)(m0 + arow) * K + k0 + akk;
      } else {
        const int tap = k0 >> 7;
        const int dy = tap / 3 - 1, dx = tap % 3 - 1;
        const int pix = m0 + arow;
        const int hs = (pix >> 7) + dy;
        const int xs = (pix & 127) + dx;
        const bool ok = (hs >= 0) && (hs < 128) && (xs >= 0) && (xs < 128);
        const size_t srcoff = (size_t)((hs << 7) | (xs & 127)) * 128 + (k0 & 127) + akk;
        asrc = ok ? A + srcoff : zbuf;
        if (MODE == 2) asrc2 = ok ? A2 + srcoff : zbuf;
      }
      gld_lds16(asrc, &As[r0 * 64]);
      if (MODE == 2) gld_lds16(asrc2, &As2[r0 * 64]);
    }
#pragma unroll
    for (int q = 0; q < BN / 32; ++q) {
      const int r0 = w * (BN / 4) + q * 8;
      const int brow = r0 + lrow;
      gld_lds16(Wt + (size_t)(n0 + brow) * K + k0 + akk, &Bs[r0 * 64]);
      if (MODE == 2)
        gld_lds16(Wt2 + (size_t)(n0 + brow) * K + k0 + akk, &Bs2[r0 * 64]);
    }
    __syncthreads();
#pragma unroll
    for (int ks = 0; ks < 64; ks += 32) {
      bf16x8 af[MI], bfv[NJ];
#pragma unroll
      for (int i = 0; i < MI; ++i)
        af[i] = *(const bf16x8*)&As[swz(arow_l + i * 16, ks + klane)];
#pragma unroll
      for (int j = 0; j < NJ; ++j)
        bfv[j] = *(const bf16x8*)&Bs[swz(brow_l + j * 16, ks + klane)];
#pragma unroll
      for (int i = 0; i < MI; ++i)
#pragma unroll
        for (int j = 0; j < NJ; ++j)
          acc[i][j] = __builtin_amdgcn_mfma_f32_16x16x32_bf16(af[i], bfv[j], acc[i][j], 0, 0, 0);
      if (MODE == 2) {
        bf16x8 af2[MI], bf2[NJ];
#pragma unroll
        for (int i = 0; i < MI; ++i)
          af2[i] = *(const bf16x8*)&As2[swz(arow_l + i * 16, ks + klane)];
#pragma unroll
        for (int j = 0; j < NJ; ++j)
          bf2[j] = *(const bf16x8*)&Bs2[swz(brow_l + j * 16, ks + klane)];
#pragma unroll
        for (int i = 0; i < MI; ++i)
#pragma unroll
          for (int j = 0; j < NJ; ++j) {
            acc[i][j] = __builtin_amdgcn_mfma_f32_16x16x32_bf16(af[i], bf2[j], acc[i][j], 0, 0, 0);
            acc[i][j] = __builtin_amdgcn_mfma_f32_16x16x32_bf16(af2[i], bfv[j], acc[i][j], 0, 0, 0);
          }
      }
    }
    __syncthreads();
  }
  // ---- epilogue ----
  float sj[NJ], ssj[NJ];
#pragma unroll
  for (int j = 0; j < NJ; ++j) { sj[j] = 0.f; ssj[j] = 0.f; }
#pragma unroll
  for (int i = 0; i < MI; ++i) {
    const int mrow = m0 + wr * (BM / 2) + i * 16 + (lane >> 4) * 4;
#pragma unroll
    for (int j = 0; j < NJ; ++j) {
      const int col = n0 + wc * (BN / 2) + j * 16 + (lane & 15);
      const float bz = bias[col];
#pragma unroll
      for (int r = 0; r < 4; ++r) {
        const int m = mrow + r;
        float v = acc[i][j][r] + bz;
        if (RES == 1) v += resid[(size_t)m * 128 + col];
        if (RES == 2) v += resid[(size_t)col * QPIX + m];
        if (RES == 3)
          v += (resid[(size_t)m * 128 + col] - mrres[col]) * mrres[128 + col];
        if (ACT == 1) v = 0.5f * v * (1.f + erff(v * 0.70710678118654752f));
        if (OBF)
          ((unsigned short*)Out)[(size_t)m * N + col] = f2b(v);
        else
          ((float*)Out)[(size_t)m * N + col] = v;
        if (STATS) {
          sj[j] += v;
          ssj[j] += v * v;
        }
      }
    }
  }
  if (STATS) {
    const int cidx = wr * 4 + (lane >> 4);
#pragma unroll
    for (int j = 0; j < NJ; ++j) {
      const int cl = wc * (BN / 2) + j * 16 + (lane & 15);
      sred[cidx][cl] = sj[j];
      ssred[cidx][cl] = ssj[j];
    }
    __syncthreads();
    if (t < BN) {
      float s = 0.f, ss = 0.f;
#pragma unroll
      for (int kk = 0; kk < BM / 8; ++kk) {
        s += sred[kk][t];
        ss += ssred[kk][t];
      }
      partial[(size_t)(n0 + t) * 256 + blockIdx.y] = s;
      partial[32768 + (size_t)(n0 + t) * 256 + blockIdx.y] = ss;
    }
  }
}

// ---------------- final stats: one block per channel, coalesced, parallel ----------------
__global__ __launch_bounds__(256) void k_stats_final(const float* __restrict__ partial,
                                                     float* __restrict__ mr) {
  __shared__ float s1[256], s2[256];
  const int c = blockIdx.x;
  const int t = threadIdx.x;
  s1[t] = partial[(size_t)c * 256 + t];
  s2[t] = partial[32768 + (size_t)c * 256 + t];
  __syncthreads();
#pragma unroll
  for (int off = 128; off > 0; off >>= 1) {
    if (t < off) {
      s1[t] += s1[t + off];
      s2[t] += s2[t + off];
    }
    __syncthreads();
  }
  if (t == 0) {
    float m = s1[0] * (1.f / 16384.f);
    float var = s2[0] * (1.f / 16384.f) - m * m;
    mr[c] = m;
    mr[128 + c] = rsqrtf(var + 1e-5f);
  }
}

// ---------------- inorm apply + offset head + projection + gather, one kernel ----------------
// 1024 blocks x 16 queries. Gather: lane owns an 8-channel slice, loops cams x corners.
__global__ __launch_bounds__(256) void k_offgather(
    const float* __restrict__ tB, const float* __restrict__ mr,
    const float* __restrict__ offw, const float* __restrict__ offb,
    const float* __restrict__ bpos, const float* __restrict__ l2i,
    const unsigned short* __restrict__ featT,
    unsigned short* __restrict__ sampled) {
  __shared__ float wT[128 * 12];
  __shared__ float bl[12];
  __shared__ float Ll[96];
  __shared__ float ml[128], rl[128];
  __shared__ float ldsq[16 * 130];
  __shared__ float offl[16 * 12];
  __shared__ float cw[16 * 24 * 4];
  __shared__ int cidx[16 * 24 * 4];
  const int t = threadIdx.x;
  const int qb = blockIdx.x * 16;
  for (int i = t; i < 1536; i += 256) wT[(i & 127) * 12 + (i >> 7)] = offw[i];
  if (t < 12) bl[t] = offb[t];
  if (t < 96) Ll[t] = l2i[t];
  if (t < 128) {
    ml[t] = mr[t];
    rl[t] = mr[128 + t];
  }
  float4 ra = *(const float4*)&tB[(size_t)qb * 128 + t * 8];
  float4 rb = *(const float4*)&tB[(size_t)qb * 128 + t * 8 + 4];
  __syncthreads();
  // phase A: normalize into ldsq
  {
    const int e = t * 8;
    const int q = e >> 7, c0 = e & 127;
    float* d = &ldsq[q * 130 + c0];
    const float va[8] = {ra.x, ra.y, ra.z, ra.w, rb.x, rb.y, rb.z, rb.w};
#pragma unroll
    for (int u = 0; u < 8; ++u) d[u] = (va[u] - ml[c0 + u]) * rl[c0 + u];
  }
  __syncthreads();
  // phase B: 192 offset dots + sigmoid
  if (t < 192) {
    const int q = t / 12, o = t - (t / 12) * 12;
    float acc = bl[o];
    for (int c = 0; c < 128; ++c) acc += ldsq[q * 130 + c] * wT[c * 12 + o];
    offl[q * 12 + o] = 1.f / (1.f + expf(-acc));
  }
  __syncthreads();
  // phase C: 384 projection items -> corner weights/indices in LDS
  const float EPSf = 1e-5f;
#pragma unroll
  for (int ii = 0; ii < 2; ++ii) {
    const int item = ii * 256 + t;
    if (item < 384) {
      const int ql = item / 24;
      const int j = item - ql * 24;
      const int p = j / 6, n = j - p * 6;
      const int q = qb + ql;
      float o0 = offl[ql * 12 + p * 3 + 0];
      float o1 = offl[ql * 12 + p * 3 + 1];
      float o2 = offl[ql * 12 + p * 3 + 2];
      float ox = o0 * ((0.25f + EPSf) * 2.f) - (0.25f + EPSf);
      float oy = o1 * ((0.25f + EPSf) * 2.f) - (0.25f + EPSf);
      float oz = o2 * ((4.f + EPSf) * 2.f) - (4.f + EPSf);
      float px = bpos[q * 3 + 0] * 102.4f - 51.2f + ox;
      float py = bpos[q * 3 + 1] * 102.4f - 51.2f + oy;
      float pz = bpos[q * 3 + 2] * 8.f - 5.f + oz;
      const float* L = Ll + n * 16;
      float c0 = L[0] * px + L[1] * py + L[2] * pz + L[3];
      float c1 = L[4] * px + L[5] * py + L[6] * pz + L[7];
      float c2 = L[8] * px + L[9] * py + L[10] * pz + L[11];
      float d = fmaxf(c2, EPSf);
      float u = (c0 / d) / 704.f;
      float v = (c1 / d) / 256.f;
      float valid = (c2 > EPSf && u > 0.f && u < 1.f && v > 0.f && v < 1.f) ? 1.f : 0.f;
      float x = u * 88.f - 0.5f;
      float y = v * 32.f - 0.5f;
      float x0 = floorf(x), y0 = floorf(y);
      float wx1 = x - x0, wy1 = y - y0;
      float wx0 = 1.f - wx1, wy0 = 1.f - wy1;
#pragma unroll
      for (int k = 0; k < 4; ++k) {
        float xf = x0 + (float)(k & 1);
        float yf = y0 + (float)(k >> 1);
        bool inb = (xf >= 0.f) && (xf <= 87.f) && (yf >= 0.f) && (yf <= 31.f);
        float xc = fminf(fmaxf(xf, 0.f), 87.f);
        float yc = fminf(fmaxf(yf, 0.f), 31.f);
        cidx[ql * 96 + j * 4 + k] = ((n * 32 + (int)yc) * 88 + (int)xc) * 128;
        float wgt = ((k & 1) ? wx1 : wx0) * ((k >> 1) ? wy1 : wy0);
        cw[ql * 96 + j * 4 + k] = inb ? wgt * valid : 0.f;
      }
    }
  }
  __syncthreads();
  // phase D: gather — lane owns 8 channels; serial over 6 cams x 4 corners
  const int e8 = (t & 15) * 8;
#pragma unroll
  for (int rep = 0; rep < 4; ++rep) {
    const int unit = rep * 16 + (t >> 4);
    const int q = unit >> 2, p = unit & 3;
    float s[8] = {0.f, 0.f, 0.f, 0.f, 0.f, 0.f, 0.f, 0.f};
    const float* cwp = &cw[q * 96 + p * 24];
    const int* cip = &cidx[q * 96 + p * 24];
#pragma unroll
    for (int cc = 0; cc < 24; ++cc) {
      const float wv = cwp[cc];
      if (wv != 0.f) {
        ushort8v v = *(const ushort8v*)&featT[(size_t)cip[cc] + e8];
#pragma unroll
        for (int u = 0; u < 8; ++u) s[u] += wv * b2f(v[u]);
      }
    }
    ushort8v o8;
#pragma unroll
    for (int u = 0; u < 8; ++u) o8[u] = f2b(s[u]);
    *(ushort8v*)&sampled[(size_t)(qb + q) * 512 + p * 128 + e8] = o8;
  }
}

// ---------------- apply: norm(a) -> bf16, vectorized ----------------
__global__ __launch_bounds__(256) void k_apply2(const float* __restrict__ a,
                                                const float* __restrict__ mr,
                                                unsigned short* __restrict__ outb) {
  const size_t i = ((size_t)blockIdx.x * 256 + threadIdx.x) * 4;
  const int c = (int)(i & 127);
  float4 v = *(const float4*)&a[i];
  ushort4 o;
  o.x = f2b((v.x - mr[c]) * mr[128 + c]);
  o.y = f2b((v.y - mr[c + 1]) * mr[128 + c + 1]);
  o.z = f2b((v.z - mr[c + 2]) * mr[128 + c + 2]);
  o.w = f2b((v.w - mr[c + 3]) * mr[128 + c + 3]);
  *(ushort4*)&outb[i] = o;
}

// ---------------- final apply: norm(a) + NHWC->NCHW via LDS tiles ----------------
__global__ __launch_bounds__(256) void k_apply_t(const float* __restrict__ a,
                                                 const float* __restrict__ mr,
                                                 float* __restrict__ out) {
  __shared__ float tile[128][33];
  __shared__ float ml[128], rl[128];
  const int t = threadIdx.x;
  const int pb = blockIdx.x * 32;
  if (t < 128) {
    ml[t] = mr[t];
    rl[t] = mr[128 + t];
  }
  __syncthreads();
#pragma unroll
  for (int j = 0; j < 16; ++j) {
    const int e = j * 256 + t;
    const int pl = e >> 7, c = e & 127;
    const size_t gi = (size_t)(pb + pl) * 128 + c;
    tile[c][pl] = (a[gi] - ml[c]) * rl[c];
  }
  __syncthreads();
  const int p = t & 31, cb = t >> 5;
#pragma unroll
  for (int j = 0; j < 16; ++j) {
    const int c = cb + j * 8;
    out[(size_t)c * QPIX + pb + p] = tile[c][p];
  }
}

extern "C" void kernel_launch(void* const* d_in, const int* in_sizes, int n_in,
                              void* d_out, int out_size, void* d_ws, size_t ws_size,
                              hipStream_t stream) {
  const float* feats = (const float*)d_in[0];
  const float* l2i   = (const float*)d_in[1];
  const float* bevq  = (const float*)d_in[2];
  const float* bpos  = (const float*)d_in[3];
  const float* w_in  = (const float*)d_in[4];
  const float* b_in  = (const float*)d_in[5];
  const float* offw  = (const float*)d_in[6];
  const float* offb  = (const float*)d_in[7];
  const float* w1    = (const float*)d_in[8];
  const float* b1    = (const float*)d_in[9];
  const float* w2    = (const float*)d_in[10];
  const float* b2    = (const float*)d_in[11];
  const float* w3    = (const float*)d_in[12];
  const float* b3    = (const float*)d_in[13];
  const float* w_out = (const float*)d_in[14];
  const float* b_out = (const float*)d_in[15];
  float* out = (float*)d_out;

  const size_t QC = (size_t)QPIX * 128;
  float* ws = (float*)d_ws;
  float* tA = ws;                         // 2,097,152  conv1 out -> conv2 out
  float* tBb = tA + QC;                   // 2,097,152  mm3 out
  float* partial = tBb + QC;              // 65,536 ([128 c][256 yblk] sum + ssq)
  float* mr1 = partial + 65536;           // 256
  float* mr2 = mr1 + 256;                 // 256
  float* mr3 = mr2 + 256;                 // 256
  float* zerof = mr3 + 256;               // 160
  unsigned short* us = (unsigned short*)(zerof + 160);
  unsigned short* S1b = us;               // 8,388,608 (sampled -> x2)
  unsigned short* S2b = S1b + 8388608;    // 8,388,608 (x1)
  unsigned short* featTb = S2b + 8388608; // 2,162,688
  unsigned short* qhi = featTb + 2162688; // 2,097,152 (conv1 hi; later q2 bf16)
  unsigned short* qlo = qhi + 2097152;    // 2,097,152
  unsigned short* w1b = qlo + 2097152;    // 262,144
  unsigned short* w2b = w1b + 262144;     // 262,144
  unsigned short* w3b = w2b + 262144;     // 65,536
  unsigned short* wob = w3b + 65536;      // 147,456
  unsigned short* wibh = wob + 147456;    // 147,456
  unsigned short* wibl = wibh + 147456;   // 147,456
  const unsigned short* zb = (const unsigned short*)zerof;

  dim3 blk(256);

  // all conversions + zero-buffer init, one dispatch
  k_cvt_all<<<4496, blk, 0, stream>>>(feats, bevq, w1, w2, w3, w_out, w_in,
                                      featTb, qhi, qlo, w1b, w2b, w3b, wob, wibh,
                                      wibl, zerof);

  // t1 = q + conv3x3(q)  (split-precision bf16 MFMA, fused stats partials)
  mfma_gemm<64, 64, 2, 0, 2, 0, 1><<<dim3(2, 256), blk, 0, stream>>>(
      qhi, qlo, wibh, wibl, b_in, bevq, nullptr, tA, partial, 128, 1152, zb);
  k_stats_final<<<128, blk, 0, stream>>>(partial, mr1);

  // inorm(t1) -> offset head -> projection -> gather, one kernel
  k_offgather<<<1024, blk, 0, stream>>>(tA, mr1, offw, offb, bpos, l2i, featTb, S1b);

  // mid MLP
  mfma_gemm<128, 128, 0, 1, 0, 1, 0><<<dim3(4, 128), blk, 0, stream>>>(
      S1b, nullptr, w1b, nullptr, b1, nullptr, nullptr, S2b, nullptr, 512, 512, zb);
  mfma_gemm<128, 128, 0, 1, 0, 1, 0><<<dim3(4, 128), blk, 0, stream>>>(
      S2b, nullptr, w2b, nullptr, b2, nullptr, nullptr, S1b, nullptr, 512, 512, zb);
  // mm3: x3 + inline-norm(t1) residual, fused stats partials
  mfma_gemm<64, 64, 0, 0, 3, 0, 1><<<dim3(2, 256), blk, 0, stream>>>(
      S1b, nullptr, w3b, nullptr, b3, tA, mr1, tBb, partial, 128, 512, zb);
  k_stats_final<<<128, blk, 0, stream>>>(partial, mr2);
  k_apply2<<<2048, blk, 0, stream>>>(tBb, mr2, qhi);  // q2 bf16 for conv2 A

  // t2 = q2 + conv3x3(q2)  (bf16 MFMA im2col, inline-norm residual, fused stats)
  mfma_gemm<64, 64, 1, 0, 3, 0, 1><<<dim3(2, 256), blk, 0, stream>>>(
      qhi, nullptr, wob, nullptr, b_out, tBb, mr2, tA, partial, 128, 1152, zb);
  k_stats_final<<<128, blk, 0, stream>>>(partial, mr3);
  k_apply_t<<<512, blk, 0, stream>>>(tA, mr3, out);
}

// Round 11
// 139.171 us; speedup vs baseline: 2.4987x; 1.0044x over previous
//
#include <hip/hip_runtime.h>
#include <math.h>

#define QPIX 16384

typedef __bf16 bf16x8 __attribute__((ext_vector_type(8)));
typedef float f32x4 __attribute__((ext_vector_type(4)));
typedef unsigned short ushort8v __attribute__((ext_vector_type(8)));

__device__ __forceinline__ unsigned short f2b(float f) {
  unsigned int x = __float_as_uint(f);
  unsigned int r = (x + 0x7fff + ((x >> 16) & 1)) >> 16;
  return (unsigned short)r;
}
__device__ __forceinline__ float b2f(unsigned short u) {
  return __uint_as_float(((unsigned int)u) << 16);
}

__device__ __forceinline__ void gld_lds16(const void* g, void* l) {
  __builtin_amdgcn_global_load_lds((__attribute__((address_space(1))) void*)(g),
                                   (__attribute__((address_space(3))) void*)(l), 16, 0, 0);
}

// swizzled element offset within a [rows][64]-bf16 LDS tile (16B-slot XOR row&7)
__device__ __forceinline__ int swz(int row, int ebase) {
  return row * 64 + ((((ebase) >> 3) ^ (row & 7)) << 3);
}

// ---------------- all input conversions in ONE dispatch (+ zero-buffer init) ----------------
__global__ __launch_bounds__(256) void k_cvt_all(
    const float* __restrict__ feats, const float* __restrict__ bevq,
    const float* __restrict__ w1, const float* __restrict__ w2,
    const float* __restrict__ w3, const float* __restrict__ wo,
    const float* __restrict__ wi, unsigned short* __restrict__ featTb,
    unsigned short* __restrict__ qhi, unsigned short* __restrict__ qlo,
    unsigned short* __restrict__ w1b, unsigned short* __restrict__ w2b,
    unsigned short* __restrict__ w3b, unsigned short* __restrict__ wob,
    unsigned short* __restrict__ wibh, unsigned short* __restrict__ wibl,
    float* __restrict__ zerof) {
  __shared__ float tile[128][33];
  const int b = blockIdx.x, t = threadIdx.x;
  if (b == 0 && t < 160) zerof[t] = 0.f;
  if (b < 528) {
    const int img = b / 88;
    const int pb = (b - img * 88) * 32;
    const int p = t & 31, cg = t >> 5;
#pragma unroll
    for (int ci = 0; ci < 16; ++ci) {
      const int c = cg * 16 + ci;
      tile[c][p] = feats[((size_t)img * 128 + c) * 2816 + pb + p];
    }
    __syncthreads();
    const int c2 = t & 127, pw = t >> 7;
#pragma unroll
    for (int pp = pw; pp < 32; pp += 2)
      featTb[(size_t)img * 2816 * 128 + (size_t)(pb + pp) * 128 + c2] = f2b(tile[c2][pp]);
  } else if (b < 1040) {
    const int pb = (b - 528) * 32;
    const int p = t & 31, cg = t >> 5;
#pragma unroll
    for (int ci = 0; ci < 16; ++ci) {
      const int c = cg * 16 + ci;
      tile[c][p] = bevq[(size_t)c * QPIX + pb + p];
    }
    __syncthreads();
    const int c2 = t & 127, pw = t >> 7;
#pragma unroll
    for (int pp = pw; pp < 32; pp += 2) {
      float v = tile[c2][pp];
      unsigned short h = f2b(v);
      qhi[(size_t)(pb + pp) * 128 + c2] = h;
      qlo[(size_t)(pb + pp) * 128 + c2] = f2b(v - b2f(h));
    }
  } else {
    const int bb = b - 1040;
    if (bb < 1024) {
      int i = bb * 256 + t;
      w1b[i] = f2b(w1[i]);
    } else if (bb < 2048) {
      int i = (bb - 1024) * 256 + t;
      w2b[i] = f2b(w2[i]);
    } else if (bb < 2304) {
      int i = (bb - 2048) * 256 + t;
      w3b[i] = f2b(w3[i]);
    } else if (bb < 2880) {
      int i = (bb - 2304) * 256 + t;
      int n = i & 127, kk = i >> 7;
      int tap = kk >> 7, ci = kk & 127;
      wob[(size_t)n * 1152 + kk] = f2b(wo[(size_t)tap * 16384 + ci * 128 + n]);
    } else {
      int i = (bb - 2880) * 256 + t;
      int n = i & 127, kk = i >> 7;
      int tap = kk >> 7, ci = kk & 127;
      float v = wi[(size_t)tap * 16384 + ci * 128 + n];
      unsigned short h = f2b(v);
      wibh[(size_t)n * 1152 + kk] = h;
      wibl[(size_t)n * 1152 + kk] = f2b(v - b2f(h));
    }
  }
}

// ---------------- bf16 MFMA GEMM: 2-phase dbuf LDS, T2 swizzle, optional fused stats ----------------
// Out[M,N] = act( A @ Wt^T + bias (+resid) ), Wt is [N][K] bf16 row-major.
// MODE: 0 plain A [M][K]; 1 conv3x3 im2col from NHWC bf16; 2 conv im2col split precision.
// ACT: 0 none, 1 exact gelu.
// RES: 0 none, 1 fp32 NHWC resid, 2 fp32 NCHW resid, 3 NHWC inline-norm resid ((resid-m)*r).
// OBF: 1 bf16 out, 0 fp32 out.
// STATS: 1 -> per-block per-channel sum/ssq to partial[(n0+c)*256 + blockIdx.y] (gridDim.y==256).
template <int BM, int BN, int MODE, int ACT, int RES, int OBF, int STATS>
__global__ __launch_bounds__(256) void mfma_gemm(
    const unsigned short* __restrict__ A, const unsigned short* __restrict__ A2,
    const unsigned short* __restrict__ Wt, const unsigned short* __restrict__ Wt2,
    const float* __restrict__ bias, const float* __restrict__ resid,
    const float* __restrict__ mrres, void* __restrict__ Out,
    float* __restrict__ partial, int N, int K,
    const unsigned short* __restrict__ zbuf) {
  constexpr int MI = BM / 32;
  constexpr int NJ = BN / 32;
  __shared__ unsigned short As[2][BM * 64];
  __shared__ unsigned short Bs[2][BN * 64];
  __shared__ unsigned short As2[(MODE == 2) ? 2 * BM * 64 : 1];
  __shared__ unsigned short Bs2[(MODE == 2) ? 2 * BN * 64 : 1];
  __shared__ float sred[STATS ? (BM / 8) : 1][STATS ? BN : 1];
  __shared__ float ssred[STATS ? (BM / 8) : 1][STATS ? BN : 1];

  const int t = threadIdx.x;
  const int lane = t & 63, w = t >> 6;
  const int wr = w >> 1, wc = w & 1;
  const int n0 = blockIdx.x * BN;
  const int m0 = blockIdx.y * BM;

  const int lrow = lane >> 3;
  const int akk = (((lane & 7) ^ (lrow & 7))) * 8;  // T2 pre-swizzled source k-slot
  const int arow_l = wr * (BM / 2) + (lane & 15);
  const int brow_l = wc * (BN / 2) + (lane & 15);
  const int klane = (lane >> 4) * 8;

  // stage one 64-wide K-tile into LDS buffer `buf`
  auto stage = [&](int buf, int k0) {
#pragma unroll
    for (int q = 0; q < BM / 32; ++q) {
      const int r0 = w * (BM / 4) + q * 8;
      const int arow = r0 + lrow;
      const unsigned short* asrc;
      const unsigned short* asrc2 = zbuf;
      if (MODE == 0) {
        asrc = A + (size_t)(m0 + arow) * K + k0 + akk;
      } else {
        const int tap = k0 >> 7;
        const int dy = tap / 3 - 1, dx = tap % 3 - 1;
        const int pix = m0 + arow;
        const int hs = (pix >> 7) + dy;
        const int xs = (pix & 127) + dx;
        const bool ok = (hs >= 0) && (hs < 128) && (xs >= 0) && (xs < 128);
        const size_t srcoff = (size_t)((hs << 7) | (xs & 127)) * 128 + (k0 & 127) + akk;
        asrc = ok ? A + srcoff : zbuf;
        if (MODE == 2) asrc2 = ok ? A2 + srcoff : zbuf;
      }
      gld_lds16(asrc, &As[buf][r0 * 64]);
      if (MODE == 2) gld_lds16(asrc2, &As2[buf * BM * 64 + r0 * 64]);
    }
#pragma unroll
    for (int q = 0; q < BN / 32; ++q) {
      const int r0 = w * (BN / 4) + q * 8;
      const int brow = r0 + lrow;
      gld_lds16(Wt + (size_t)(n0 + brow) * K + k0 + akk, &Bs[buf][r0 * 64]);
      if (MODE == 2)
        gld_lds16(Wt2 + (size_t)(n0 + brow) * K + k0 + akk, &Bs2[buf * BN * 64 + r0 * 64]);
    }
  };

  f32x4 acc[MI][NJ];
#pragma unroll
  for (int i = 0; i < MI; ++i)
#pragma unroll
    for (int j = 0; j < NJ; ++j) acc[i][j] = (f32x4){0.f, 0.f, 0.f, 0.f};

  stage(0, 0);
  __syncthreads();
  int buf = 0;
  for (int k0 = 0; k0 < K; k0 += 64) {
    if (k0 + 64 < K) stage(buf ^ 1, k0 + 64);  // loads fly under the MFMAs below
#pragma unroll
    for (int ks = 0; ks < 64; ks += 32) {
      bf16x8 af[MI], bfv[NJ];
#pragma unroll
      for (int i = 0; i < MI; ++i)
        af[i] = *(const bf16x8*)&As[buf][swz(arow_l + i * 16, ks + klane)];
#pragma unroll
      for (int j = 0; j < NJ; ++j)
        bfv[j] = *(const bf16x8*)&Bs[buf][swz(brow_l + j * 16, ks + klane)];
#pragma unroll
      for (int i = 0; i < MI; ++i)
#pragma unroll
        for (int j = 0; j < NJ; ++j)
          acc[i][j] = __builtin_amdgcn_mfma_f32_16x16x32_bf16(af[i], bfv[j], acc[i][j], 0, 0, 0);
      if (MODE == 2) {
        bf16x8 af2[MI], bf2[NJ];
#pragma unroll
        for (int i = 0; i < MI; ++i)
          af2[i] = *(const bf16x8*)&As2[buf * BM * 64 + swz(arow_l + i * 16, ks + klane)];
#pragma unroll
        for (int j = 0; j < NJ; ++j)
          bf2[j] = *(const bf16x8*)&Bs2[buf * BN * 64 + swz(brow_l + j * 16, ks + klane)];
#pragma unroll
        for (int i = 0; i < MI; ++i)
#pragma unroll
          for (int j = 0; j < NJ; ++j) {
            acc[i][j] = __builtin_amdgcn_mfma_f32_16x16x32_bf16(af[i], bf2[j], acc[i][j], 0, 0, 0);
            acc[i][j] = __builtin_amdgcn_mfma_f32_16x16x32_bf16(af2[i], bfv[j], acc[i][j], 0, 0, 0);
          }
      }
    }
    __syncthreads();  // publishes buf^1 (vmcnt drain) + retires buf reads
    buf ^= 1;
  }
  // ---- epilogue ----
  float sj[NJ], ssj[NJ];
#pragma unroll
  for (int j = 0; j < NJ; ++j) { sj[j] = 0.f; ssj[j] = 0.f; }
#pragma unroll
  for (int i = 0; i < MI; ++i) {
    const int mrow = m0 + wr * (BM / 2) + i * 16 + (lane >> 4) * 4;
#pragma unroll
    for (int j = 0; j < NJ; ++j) {
      const int col = n0 + wc * (BN / 2) + j * 16 + (lane & 15);
      const float bz = bias[col];
#pragma unroll
      for (int r = 0; r < 4; ++r) {
        const int m = mrow + r;
        float v = acc[i][j][r] + bz;
        if (RES == 1) v += resid[(size_t)m * 128 + col];
        if (RES == 2) v += resid[(size_t)col * QPIX + m];
        if (RES == 3)
          v += (resid[(size_t)m * 128 + col] - mrres[col]) * mrres[128 + col];
        if (ACT == 1) v = 0.5f * v * (1.f + erff(v * 0.70710678118654752f));
        if (OBF)
          ((unsigned short*)Out)[(size_t)m * N + col] = f2b(v);
        else
          ((float*)Out)[(size_t)m * N + col] = v;
        if (STATS) {
          sj[j] += v;
          ssj[j] += v * v;
        }
      }
    }
  }
  if (STATS) {
    const int cidx = wr * 4 + (lane >> 4);
#pragma unroll
    for (int j = 0; j < NJ; ++j) {
      const int cl = wc * (BN / 2) + j * 16 + (lane & 15);
      sred[cidx][cl] = sj[j];
      ssred[cidx][cl] = ssj[j];
    }
    __syncthreads();
    if (t < BN) {
      float s = 0.f, ss = 0.f;
#pragma unroll
      for (int kk = 0; kk < BM / 8; ++kk) {
        s += sred[kk][t];
        ss += ssred[kk][t];
      }
      partial[(size_t)(n0 + t) * 256 + blockIdx.y] = s;
      partial[32768 + (size_t)(n0 + t) * 256 + blockIdx.y] = ss;
    }
  }
}

// ---------------- final stats: one block per channel, coalesced, parallel ----------------
__global__ __launch_bounds__(256) void k_stats_final(const float* __restrict__ partial,
                                                     float* __restrict__ mr) {
  __shared__ float s1[256], s2[256];
  const int c = blockIdx.x;
  const int t = threadIdx.x;
  s1[t] = partial[(size_t)c * 256 + t];
  s2[t] = partial[32768 + (size_t)c * 256 + t];
  __syncthreads();
#pragma unroll
  for (int off = 128; off > 0; off >>= 1) {
    if (t < off) {
      s1[t] += s1[t + off];
      s2[t] += s2[t + off];
    }
    __syncthreads();
  }
  if (t == 0) {
    float m = s1[0] * (1.f / 16384.f);
    float var = s2[0] * (1.f / 16384.f) - m * m;
    mr[c] = m;
    mr[128 + c] = rsqrtf(var + 1e-5f);
  }
}

// ---------------- inorm apply + offset head + projection + gather, one kernel ----------------
// 1024 blocks x 16 queries. Gather: lane owns an 8-channel slice, loops cams x corners.
__global__ __launch_bounds__(256) void k_offgather(
    const float* __restrict__ tB, const float* __restrict__ mr,
    const float* __restrict__ offw, const float* __restrict__ offb,
    const float* __restrict__ bpos, const float* __restrict__ l2i,
    const unsigned short* __restrict__ featT,
    unsigned short* __restrict__ sampled) {
  __shared__ float wT[128 * 12];
  __shared__ float bl[12];
  __shared__ float Ll[96];
  __shared__ float ml[128], rl[128];
  __shared__ float ldsq[16 * 130];
  __shared__ float offl[16 * 12];
  __shared__ float cw[16 * 24 * 4];
  __shared__ int cidx[16 * 24 * 4];
  const int t = threadIdx.x;
  const int qb = blockIdx.x * 16;
  for (int i = t; i < 1536; i += 256) wT[(i & 127) * 12 + (i >> 7)] = offw[i];
  if (t < 12) bl[t] = offb[t];
  if (t < 96) Ll[t] = l2i[t];
  if (t < 128) {
    ml[t] = mr[t];
    rl[t] = mr[128 + t];
  }
  float4 ra = *(const float4*)&tB[(size_t)qb * 128 + t * 8];
  float4 rb = *(const float4*)&tB[(size_t)qb * 128 + t * 8 + 4];
  __syncthreads();
  // phase A: normalize into ldsq
  {
    const int e = t * 8;
    const int q = e >> 7, c0 = e & 127;
    float* d = &ldsq[q * 130 + c0];
    const float va[8] = {ra.x, ra.y, ra.z, ra.w, rb.x, rb.y, rb.z, rb.w};
#pragma unroll
    for (int u = 0; u < 8; ++u) d[u] = (va[u] - ml[c0 + u]) * rl[c0 + u];
  }
  __syncthreads();
  // phase B: 192 offset dots + sigmoid
  if (t < 192) {
    const int q = t / 12, o = t - (t / 12) * 12;
    float acc = bl[o];
    for (int c = 0; c < 128; ++c) acc += ldsq[q * 130 + c] * wT[c * 12 + o];
    offl[q * 12 + o] = 1.f / (1.f + expf(-acc));
  }
  __syncthreads();
  // phase C: 384 projection items -> corner weights/indices in LDS
  const float EPSf = 1e-5f;
#pragma unroll
  for (int ii = 0; ii < 2; ++ii) {
    const int item = ii * 256 + t;
    if (item < 384) {
      const int ql = item / 24;
      const int j = item - ql * 24;
      const int p = j / 6, n = j - p * 6;
      const int q = qb + ql;
      float o0 = offl[ql * 12 + p * 3 + 0];
      float o1 = offl[ql * 12 + p * 3 + 1];
      float o2 = offl[ql * 12 + p * 3 + 2];
      float ox = o0 * ((0.25f + EPSf) * 2.f) - (0.25f + EPSf);
      float oy = o1 * ((0.25f + EPSf) * 2.f) - (0.25f + EPSf);
      float oz = o2 * ((4.f + EPSf) * 2.f) - (4.f + EPSf);
      float px = bpos[q * 3 + 0] * 102.4f - 51.2f + ox;
      float py = bpos[q * 3 + 1] * 102.4f - 51.2f + oy;
      float pz = bpos[q * 3 + 2] * 8.f - 5.f + oz;
      const float* L = Ll + n * 16;
      float c0 = L[0] * px + L[1] * py + L[2] * pz + L[3];
      float c1 = L[4] * px + L[5] * py + L[6] * pz + L[7];
      float c2 = L[8] * px + L[9] * py + L[10] * pz + L[11];
      float d = fmaxf(c2, EPSf);
      float u = (c0 / d) / 704.f;
      float v = (c1 / d) / 256.f;
      float valid = (c2 > EPSf && u > 0.f && u < 1.f && v > 0.f && v < 1.f) ? 1.f : 0.f;
      float x = u * 88.f - 0.5f;
      float y = v * 32.f - 0.5f;
      float x0 = floorf(x), y0 = floorf(y);
      float wx1 = x - x0, wy1 = y - y0;
      float wx0 = 1.f - wx1, wy0 = 1.f - wy1;
#pragma unroll
      for (int k = 0; k < 4; ++k) {
        float xf = x0 + (float)(k & 1);
        float yf = y0 + (float)(k >> 1);
        bool inb = (xf >= 0.f) && (xf <= 87.f) && (yf >= 0.f) && (yf <= 31.f);
        float xc = fminf(fmaxf(xf, 0.f), 87.f);
        float yc = fminf(fmaxf(yf, 0.f), 31.f);
        cidx[ql * 96 + j * 4 + k] = ((n * 32 + (int)yc) * 88 + (int)xc) * 128;
        float wgt = ((k & 1) ? wx1 : wx0) * ((k >> 1) ? wy1 : wy0);
        cw[ql * 96 + j * 4 + k] = inb ? wgt * valid : 0.f;
      }
    }
  }
  __syncthreads();
  // phase D: gather — lane owns 8 channels; serial over 6 cams x 4 corners
  const int e8 = (t & 15) * 8;
#pragma unroll
  for (int rep = 0; rep < 4; ++rep) {
    const int unit = rep * 16 + (t >> 4);
    const int q = unit >> 2, p = unit & 3;
    float s[8] = {0.f, 0.f, 0.f, 0.f, 0.f, 0.f, 0.f, 0.f};
    const float* cwp = &cw[q * 96 + p * 24];
    const int* cip = &cidx[q * 96 + p * 24];
#pragma unroll
    for (int cc = 0; cc < 24; ++cc) {
      const float wv = cwp[cc];
      if (wv != 0.f) {
        ushort8v v = *(const ushort8v*)&featT[(size_t)cip[cc] + e8];
#pragma unroll
        for (int u = 0; u < 8; ++u) s[u] += wv * b2f(v[u]);
      }
    }
    ushort8v o8;
#pragma unroll
    for (int u = 0; u < 8; ++u) o8[u] = f2b(s[u]);
    *(ushort8v*)&sampled[(size_t)(qb + q) * 512 + p * 128 + e8] = o8;
  }
}

// ---------------- apply: norm(a) -> bf16, vectorized ----------------
__global__ __launch_bounds__(256) void k_apply2(const float* __restrict__ a,
                                                const float* __restrict__ mr,
                                                unsigned short* __restrict__ outb) {
  const size_t i = ((size_t)blockIdx.x * 256 + threadIdx.x) * 4;
  const int c = (int)(i & 127);
  float4 v = *(const float4*)&a[i];
  ushort4 o;
  o.x = f2b((v.x - mr[c]) * mr[128 + c]);
  o.y = f2b((v.y - mr[c + 1]) * mr[128 + c + 1]);
  o.z = f2b((v.z - mr[c + 2]) * mr[128 + c + 2]);
  o.w = f2b((v.w - mr[c + 3]) * mr[128 + c + 3]);
  *(ushort4*)&outb[i] = o;
}

// ---------------- final apply: norm(a) + NHWC->NCHW via LDS tiles ----------------
__global__ __launch_bounds__(256) void k_apply_t(const float* __restrict__ a,
                                                 const float* __restrict__ mr,
                                                 float* __restrict__ out) {
  __shared__ float tile[128][33];
  __shared__ float ml[128], rl[128];
  const int t = threadIdx.x;
  const int pb = blockIdx.x * 32;
  if (t < 128) {
    ml[t] = mr[t];
    rl[t] = mr[128 + t];
  }
  __syncthreads();
#pragma unroll
  for (int j = 0; j < 16; ++j) {
    const int e = j * 256 + t;
    const int pl = e >> 7, c = e & 127;
    const size_t gi = (size_t)(pb + pl) * 128 + c;
    tile[c][pl] = (a[gi] - ml[c]) * rl[c];
  }
  __syncthreads();
  const int p = t & 31, cb = t >> 5;
#pragma unroll
  for (int j = 0; j < 16; ++j) {
    const int c = cb + j * 8;
    out[(size_t)c * QPIX + pb + p] = tile[c][p];
  }
}

extern "C" void kernel_launch(void* const* d_in, const int* in_sizes, int n_in,
                              void* d_out, int out_size, void* d_ws, size_t ws_size,
                              hipStream_t stream) {
  const float* feats = (const float*)d_in[0];
  const float* l2i   = (const float*)d_in[1];
  const float* bevq  = (const float*)d_in[2];
  const float* bpos  = (const float*)d_in[3];
  const float* w_in  = (const float*)d_in[4];
  const float* b_in  = (const float*)d_in[5];
  const float* offw  = (const float*)d_in[6];
  const float* offb  = (const float*)d_in[7];
  const float* w1    = (const float*)d_in[8];
  const float* b1    = (const float*)d_in[9];
  const float* w2    = (const float*)d_in[10];
  const float* b2    = (const float*)d_in[11];
  const float* w3    = (const float*)d_in[12];
  const float* b3    = (const float*)d_in[13];
  const float* w_out = (const float*)d_in[14];
  const float* b_out = (const float*)d_in[15];
  float* out = (float*)d_out;

  const size_t QC = (size_t)QPIX * 128;
  float* ws = (float*)d_ws;
  float* tA = ws;                         // 2,097,152  conv1 out -> conv2 out
  float* tBb = tA + QC;                   // 2,097,152  mm3 out
  float* partial = tBb + QC;              // 65,536 ([128 c][256 yblk] sum + ssq)
  float* mr1 = partial + 65536;           // 256
  float* mr2 = mr1 + 256;                 // 256
  float* mr3 = mr2 + 256;                 // 256
  float* zerof = mr3 + 256;               // 160
  unsigned short* us = (unsigned short*)(zerof + 160);
  unsigned short* S1b = us;               // 8,388,608 (sampled -> x2)
  unsigned short* S2b = S1b + 8388608;    // 8,388,608 (x1)
  unsigned short* featTb = S2b + 8388608; // 2,162,688
  unsigned short* qhi = featTb + 2162688; // 2,097,152 (conv1 hi; later q2 bf16)
  unsigned short* qlo = qhi + 2097152;    // 2,097,152
  unsigned short* w1b = qlo + 2097152;    // 262,144
  unsigned short* w2b = w1b + 262144;     // 262,144
  unsigned short* w3b = w2b + 262144;     // 65,536
  unsigned short* wob = w3b + 65536;      // 147,456
  unsigned short* wibh = wob + 147456;    // 147,456
  unsigned short* wibl = wibh + 147456;   // 147,456
  const unsigned short* zb = (const unsigned short*)zerof;

  dim3 blk(256);

  // all conversions + zero-buffer init, one dispatch
  k_cvt_all<<<4496, blk, 0, stream>>>(feats, bevq, w1, w2, w3, w_out, w_in,
                                      featTb, qhi, qlo, w1b, w2b, w3b, wob, wibh,
                                      wibl, zerof);

  // t1 = q + conv3x3(q)  (split-precision bf16 MFMA, 2-phase dbuf, fused stats)
  mfma_gemm<64, 64, 2, 0, 2, 0, 1><<<dim3(2, 256), blk, 0, stream>>>(
      qhi, qlo, wibh, wibl, b_in, bevq, nullptr, tA, partial, 128, 1152, zb);
  k_stats_final<<<128, blk, 0, stream>>>(partial, mr1);

  // inorm(t1) -> offset head -> projection -> gather, one kernel
  k_offgather<<<1024, blk, 0, stream>>>(tA, mr1, offw, offb, bpos, l2i, featTb, S1b);

  // mid MLP
  mfma_gemm<128, 128, 0, 1, 0, 1, 0><<<dim3(4, 128), blk, 0, stream>>>(
      S1b, nullptr, w1b, nullptr, b1, nullptr, nullptr, S2b, nullptr, 512, 512, zb);
  mfma_gemm<128, 128, 0, 1, 0, 1, 0><<<dim3(4, 128), blk, 0, stream>>>(
      S2b, nullptr, w2b, nullptr, b2, nullptr, nullptr, S1b, nullptr, 512, 512, zb);
  // mm3: x3 + inline-norm(t1) residual, fused stats partials
  mfma_gemm<64, 64, 0, 0, 3, 0, 1><<<dim3(2, 256), blk, 0, stream>>>(
      S1b, nullptr, w3b, nullptr, b3, tA, mr1, tBb, partial, 128, 512, zb);
  k_stats_final<<<128, blk, 0, stream>>>(partial, mr2);
  k_apply2<<<2048, blk, 0, stream>>>(tBb, mr2, qhi);  // q2 bf16 for conv2 A

  // t2 = q2 + conv3x3(q2)  (bf16 MFMA im2col, inline-norm residual, fused stats)
  mfma_gemm<64, 64, 1, 0, 3, 0, 1><<<dim3(2, 256), blk, 0, stream>>>(
      qhi, nullptr, wob, nullptr, b_out, tBb, mr2, tA, partial, 128, 1152, zb);
  k_stats_final<<<128, blk, 0, stream>>>(partial, mr3);
  k_apply_t<<<512, blk, 0, stream>>>(tA, mr3, out);
}